// Round 14
// baseline (21.676 us; speedup 1.0000x reference)
//
#include <hip/hip_runtime.h>
#include <hip/hip_bf16.h>

typedef __attribute__((ext_vector_type(8))) short short8;
typedef __attribute__((ext_vector_type(4))) float f32x4;
typedef unsigned int u32;
typedef __attribute__((ext_vector_type(4))) unsigned int u32x4;

#define NN 1024

#define LFENCE { asm volatile("s_waitcnt lgkmcnt(0)" ::: "memory"); __builtin_amdgcn_sched_barrier(0); }

// R11-verified pack: one u32 = cvt_pk of two row values (row order sum-invariant).
#define PKROW(DST, TA, TB) { \
  float va_ = fmaxf(bx_ + (TA), 0.0f), vb_ = fmaxf(bx_ + (TB), 0.0f); \
  asm("v_cvt_pk_bf16_f32 %0, %1, %2" : "=v"(DST) : "v"(va_), "v"(vb_)); }

#define PK3(KA,KB,KC, BX) { const float bx_ = (BX); \
  PKROW(KA, T0_, T1_) PKROW(KB, T2_, T3_) PKROW(KC, T4_, T5_) }

// One supergroup -> 18 packed row-pair values k0..k17 (R11-verified algebra).
#define SGCOMP(A0,A1,A2, M0,M1,M2) { \
  const float f0_ = b1v + P[(A0)*6+0]; \
  const float f1_ = b1v + P[(A1)*6+0]; \
  const float f2_ = b1v + P[(A2)*6+0]; \
  const float g12_ = P[(A1)*6+1] + P[(A2)*6+2]; \
  const float g21_ = P[(A2)*6+1] + P[(A1)*6+2]; \
  const float g02_ = P[(A0)*6+1] + P[(A2)*6+2]; \
  const float g20_ = P[(A2)*6+1] + P[(A0)*6+2]; \
  const float g01_ = P[(A0)*6+1] + P[(A1)*6+2]; \
  const float g10_ = P[(A1)*6+1] + P[(A0)*6+2]; \
  const float e0_ = P[(M0)*6+3], e1_ = P[(M1)*6+3], e2_ = P[(M2)*6+3]; \
  const float h12_ = P[(M1)*6+4] + P[(M2)*6+5]; \
  const float h21_ = P[(M2)*6+4] + P[(M1)*6+5]; \
  const float h02_ = P[(M0)*6+4] + P[(M2)*6+5]; \
  const float h20_ = P[(M2)*6+4] + P[(M0)*6+5]; \
  const float h01_ = P[(M0)*6+4] + P[(M1)*6+5]; \
  const float h10_ = P[(M1)*6+4] + P[(M0)*6+5]; \
  const float T0_ = e0_+h12_, T1_ = e0_+h21_, T2_ = e1_+h02_; \
  const float T3_ = e1_+h20_, T4_ = e2_+h01_, T5_ = e2_+h10_; \
  PK3(k0,k1,k2,   f0_+g12_)  PK3(k3,k4,k5,   f0_+g21_) \
  PK3(k6,k7,k8,   f1_+g02_)  PK3(k9,k10,k11, f1_+g20_) \
  PK3(k12,k13,k14,f2_+g01_)  PK3(k15,k16,k17,f2_+g10_) }

// 16 slot-writes via 8 shared bases (swz class j) -> LLVM fuses (j, j+8) into
// ds_write2st64_b32. Layout idx = r2*64 + (lane^((r2&7)<<3)) — R11-verified.
#define WRT16 { \
  bp0[0*64]=k0;  bp0[8*64]=k8;  \
  bp1[1*64]=k1;  bp1[9*64]=k9;  \
  bp2[2*64]=k2;  bp2[10*64]=k10; \
  bp3[3*64]=k3;  bp3[11*64]=k11; \
  bp4[4*64]=k4;  bp4[12*64]=k12; \
  bp5[5*64]=k5;  bp5[13*64]=k13; \
  bp6[6*64]=k6;  bp6[14*64]=k14; \
  bp7[7*64]=k7;  bp7[15*64]=k15; }

#define WOV { \
  wb[16*64 + (lane ^ 0)] = k16; \
  wb[17*64 + (lane ^ 8)] = k17; }

// hi-only layer-2 tile: 4 MFMA + relu-accumulate (R9/R11-verified).
#define MFMA4T(A0_, A1_) do { \
  f32x4 c0_ = {b2v0,b2v0,b2v0,b2v0}; \
  f32x4 c1_ = {b2v1,b2v1,b2v1,b2v1}; \
  c0_ = __builtin_amdgcn_mfma_f32_16x16x32_bf16(A0_, bh00, c0_, 0,0,0); \
  c0_ = __builtin_amdgcn_mfma_f32_16x16x32_bf16(A1_, bh10, c0_, 0,0,0); \
  c1_ = __builtin_amdgcn_mfma_f32_16x16x32_bf16(A0_, bh01, c1_, 0,0,0); \
  c1_ = __builtin_amdgcn_mfma_f32_16x16x32_bf16(A1_, bh11, c1_, 0,0,0); \
  acc0[0]+=fmaxf(c0_[0],0.f); acc0[1]+=fmaxf(c0_[1],0.f); \
  acc0[2]+=fmaxf(c0_[2],0.f); acc0[3]+=fmaxf(c0_[3],0.f); \
  acc1[0]+=fmaxf(c1_[0],0.f); acc1[1]+=fmaxf(c1_[1],0.f); \
  acc1[2]+=fmaxf(c1_[2],0.f); acc1[3]+=fmaxf(c1_[3],0.f); \
} while(0)

// Queue all 12 b128 reads (blocks r2 0..23; 18..23 zero pad) — R11-verified.
#define RQ { \
  q0  = *(const u32x4*)&wb[e0b];         q1  = *(const u32x4*)&wb[e0b+4]; \
  q2  = *(const u32x4*)&wb[e1b];         q3  = *(const u32x4*)&wb[e1b+4]; \
  q4  = *(const u32x4*)&wb[512+e0b];     q5  = *(const u32x4*)&wb[512+e0b+4]; \
  q6  = *(const u32x4*)&wb[512+e1b];     q7  = *(const u32x4*)&wb[512+e1b+4]; \
  q8  = *(const u32x4*)&wb[1024+e0b];    q9  = *(const u32x4*)&wb[1024+e0b+4]; \
  q10 = *(const u32x4*)&wb[1024+e1b];    q11 = *(const u32x4*)&wb[1024+e1b+4]; }

#define FRAG(dst, qa_, qb_) { \
  u32x4 t_; \
  t_[0] = __builtin_amdgcn_perm(qa_[1], qa_[0], sel); \
  t_[1] = __builtin_amdgcn_perm(qa_[3], qa_[2], sel); \
  t_[2] = __builtin_amdgcn_perm(qb_[1], qb_[0], sel); \
  t_[3] = __builtin_amdgcn_perm(qb_[3], qb_[2], sel); \
  dst = __builtin_bit_cast(short8, t_); }

#define M3 { \
  short8 A0f_, A1f_; \
  FRAG(A0f_, q0, q1);   FRAG(A1f_, q2, q3);   MFMA4T(A0f_, A1f_); \
  FRAG(A0f_, q4, q5);   FRAG(A1f_, q6, q7);   MFMA4T(A0f_, A1f_); \
  FRAG(A0f_, q8, q9);   FRAG(A1f_, q10, q11); MFMA4T(A0f_, A1f_); }

// One chunk: 1 supergroup -> 18 slot-writes, 12 b128 reads, 1 fence, 3 tiles.
#define CHUNK1(A0,A1,A2, M0,M1,M2) { \
  SGCOMP(A0,A1,A2, M0,M1,M2); WRT16; WOV; RQ; LFENCE; M3; }

#define MKB(dst_h, KH, NIDX) do { \
  _Pragma("unroll") \
  for (int e_ = 0; e_ < 8; ++e_) { \
    float f_ = W2[((KH)*32 + kg*8 + e_)*32 + 16*(NIDX) + colb]; \
    __hip_bfloat16 hi_ = __float2bfloat16(f_); \
    dst_h[e_] = *(short*)&hi_; \
  } \
} while(0)

// (256,3): VGPR cap ~170 (live set ~130-140, no spill expected), 3 blocks/CU
// = 12 waves/CU = 3 waves/SIMD — the un-confounded occupancy test.
// (256,4)'s 128-VGPR... R5 showed a too-tight cap spills catastrophically.
__global__ __launch_bounds__(256, 3) void symm_mlp_kernel(
    const float* __restrict__ x,
    const float* __restrict__ W1, const float* __restrict__ b1,
    const float* __restrict__ W2, const float* __restrict__ b2,
    const float* __restrict__ W3, const float* __restrict__ b3,
    const int* __restrict__ idx,
    float* __restrict__ out)
{
    __shared__ u32 h1s[4][24 * 64];   // per-wave single buffer, pair-packed (6 KB)
    __shared__ float redbuf[4][32];

    const int tid   = threadIdx.x;
    const int lane  = tid & 63;
    const int wv    = tid >> 6;
    const int batch = blockIdx.x;

    const float b1v = b1[lane];
    const int colb = lane & 15, kg = lane >> 4;
    const float b2v0 = b2[colb];
    const float b2v1 = b2[16 + colb];

    // ---- P[k*6+j] = pts[k] . W1[3j:3j+3, h=lane] (registers, R11-verified);
    //      w1c/px scoped so their 36 regs die after P-build ----
    float P[36];
    {
        int pidx[6];
        #pragma unroll
        for (int k = 0; k < 6; ++k) pidx[k] = idx[batch * 6 + k];

        float px[6][3];
        #pragma unroll
        for (int k = 0; k < 6; ++k)
            #pragma unroll
            for (int d = 0; d < 3; ++d) px[k][d] = x[(batch * NN + pidx[k]) * 3 + d];

        float w1c[18];
        #pragma unroll
        for (int r = 0; r < 18; ++r) w1c[r] = W1[r * 64 + lane];

        #pragma unroll
        for (int k = 0; k < 6; ++k)
        #pragma unroll
        for (int j = 0; j < 6; ++j)
            P[k*6+j] = fmaf(px[k][2], w1c[3*j+2], fmaf(px[k][1], w1c[3*j+1], px[k][0] * w1c[3*j+0]));
    }

    // ---- W2 hi-bf16 B-fragments (R9-verified accuracy) ----
    short8 bh00, bh10, bh01, bh11;
    MKB(bh00, 0, 0);
    MKB(bh10, 1, 0);
    MKB(bh01, 0, 1);
    MKB(bh11, 1, 1);

    // ---- zero pad blocks r2=18..23 once (never overwritten) ----
    u32* wb = &h1s[wv][0];
    wb[18*64+(lane^16)]=0u; wb[19*64+(lane^24)]=0u; wb[20*64+(lane^32)]=0u;
    wb[21*64+(lane^40)]=0u; wb[22*64+(lane^48)]=0u; wb[23*64+(lane^56)]=0u;

    // Write bases per swizzle class (R13-verified write2st64 pairing).
    u32* bp0 = wb + (lane ^ 0);
    u32* bp1 = wb + (lane ^ 8);
    u32* bp2 = wb + (lane ^ 16);
    u32* bp3 = wb + (lane ^ 24);
    u32* bp4 = wb + (lane ^ 32);
    u32* bp5 = wb + (lane ^ 40);
    u32* bp6 = wb + (lane ^ 48);
    u32* bp7 = wb + (lane ^ 56);

    // A-fragment read bases (u32 units) — R11-verified.
    const int r2l = (lane & 15) >> 1;
    const int sm  = r2l << 3;
    const int e0b = r2l * 64 + ((kg * 8) ^ sm);
    const int e1b = r2l * 64 + ((32 + kg * 8) ^ sm);
    const u32 sel = (lane & 1) ? 0x07060302u : 0x05040100u;

    f32x4 acc0 = {0.f,0.f,0.f,0.f}, acc1 = {0.f,0.f,0.f,0.f};
    u32x4 q0,q1,q2,q3,q4,q5,q6,q7,q8,q9,q10,q11;
    u32 k0,k1,k2,k3,k4,k5,k6,k7,k8,k9,k10,k11,k12,k13,k14,k15,k16,k17;

    // ---- 5 supergroups per wave (all 20 covered exactly once) ----
    if (wv == 0) {
        CHUNK1(0,1,2, 3,4,5); CHUNK1(0,1,3, 2,4,5); CHUNK1(0,1,4, 2,3,5);
        CHUNK1(0,1,5, 2,3,4); CHUNK1(0,2,3, 1,4,5);
    } else if (wv == 1) {
        CHUNK1(0,2,4, 1,3,5); CHUNK1(0,2,5, 1,3,4); CHUNK1(0,3,4, 1,2,5);
        CHUNK1(0,3,5, 1,2,4); CHUNK1(0,4,5, 1,2,3);
    } else if (wv == 2) {
        CHUNK1(1,2,3, 0,4,5); CHUNK1(1,2,4, 0,3,5); CHUNK1(1,2,5, 0,3,4);
        CHUNK1(1,3,4, 0,2,5); CHUNK1(1,3,5, 0,2,4);
    } else {
        CHUNK1(1,4,5, 0,2,3); CHUNK1(2,3,4, 0,1,5); CHUNK1(2,3,5, 0,1,4);
        CHUNK1(2,4,5, 0,1,3); CHUNK1(3,4,5, 0,1,2);
    }

    // ---- wave-level reduce (180 real + 60 zero-pad rows each) ----
    float s0 = acc0[0] + acc0[1] + acc0[2] + acc0[3];
    float s1 = acc1[0] + acc1[1] + acc1[2] + acc1[3];
    s0 += __shfl_xor(s0, 16, 64);  s0 += __shfl_xor(s0, 32, 64);
    s1 += __shfl_xor(s1, 16, 64);  s1 += __shfl_xor(s1, 32, 64);
    // pad rows contributed relu(b2[col]) each: 5 chunks x 12 rows = 60
    s0 -= 60.0f * fmaxf(b2v0, 0.0f);
    s1 -= 60.0f * fmaxf(b2v1, 0.0f);

    if (lane < 16)       redbuf[wv][lane] = s0;
    else if (lane < 32)  redbuf[wv][lane] = s1;
    __syncthreads();

    // ---- combine waves + layer 3, once per batch ----
    if (tid < 40) {
        float m[32];
        #pragma unroll
        for (int c = 0; c < 32; ++c)
            m[c] = (redbuf[0][c] + redbuf[1][c] + redbuf[2][c] + redbuf[3][c]) * (1.0f / 720.0f);
        float y = b3[tid];
        #pragma unroll
        for (int c = 0; c < 32; ++c) y = fmaf(m[c], W3[c * 40 + tid], y);
        out[batch * 40 + tid] = y;
    }
}

extern "C" void kernel_launch(void* const* d_in, const int* in_sizes, int n_in,
                              void* d_out, int out_size, void* d_ws, size_t ws_size,
                              hipStream_t stream) {
    const float* x  = (const float*)d_in[0];
    const float* W1 = (const float*)d_in[1];
    const float* b1 = (const float*)d_in[2];
    const float* W2 = (const float*)d_in[3];
    const float* b2 = (const float*)d_in[4];
    const float* W3 = (const float*)d_in[5];
    const float* b3 = (const float*)d_in[6];
    const int* idx   = (const int*)d_in[7];
    // d_in[8] (perms) is a compile-time constant (all perms of 0..5); the mean
    // over permutations is order-invariant, so enumeration is hard-coded.
    float* out = (float*)d_out;

    symm_mlp_kernel<<<1024, 256, 0, stream>>>(x, W1, b1, W2, b2, W3, b3, idx, out);
}

// Round 15
// 18.947 us; speedup vs baseline: 1.1441x; 1.1441x over previous
//
#include <hip/hip_runtime.h>
#include <hip/hip_bf16.h>

typedef __attribute__((ext_vector_type(8))) short short8;
typedef __attribute__((ext_vector_type(4))) float f32x4;
typedef unsigned int u32;
typedef __attribute__((ext_vector_type(4))) unsigned int u32x4;

#define NN 1024

// Soft fence: pins memory-op (DS) issue order at the compiler level with ZERO
// instructions and no hard waitcnt drain. Same-wave DS ops execute in order on
// the pipe (empirically verified R7-R13: reads issued before any wait return
// fresh data); the compiler inserts counted lgkmcnt before MFMA operand use.
#define SFENCE { asm volatile("" ::: "memory"); }

// R11-verified pack: one u32 = cvt_pk of two row values (row order sum-invariant).
#define PKROW(DST, TA, TB) { \
  float va_ = fmaxf(bx_ + (TA), 0.0f), vb_ = fmaxf(bx_ + (TB), 0.0f); \
  asm("v_cvt_pk_bf16_f32 %0, %1, %2" : "=v"(DST) : "v"(va_), "v"(vb_)); }

#define PK3(KA,KB,KC, BX) { const float bx_ = (BX); \
  PKROW(KA, T0_, T1_) PKROW(KB, T2_, T3_) PKROW(KC, T4_, T5_) }

// One supergroup -> 18 packed row-pair values k0..k17 (R11-verified algebra).
#define SGCOMP(A0,A1,A2, M0,M1,M2) { \
  const float f0_ = b1v + P[(A0)*6+0]; \
  const float f1_ = b1v + P[(A1)*6+0]; \
  const float f2_ = b1v + P[(A2)*6+0]; \
  const float g12_ = P[(A1)*6+1] + P[(A2)*6+2]; \
  const float g21_ = P[(A2)*6+1] + P[(A1)*6+2]; \
  const float g02_ = P[(A0)*6+1] + P[(A2)*6+2]; \
  const float g20_ = P[(A2)*6+1] + P[(A0)*6+2]; \
  const float g01_ = P[(A0)*6+1] + P[(A1)*6+2]; \
  const float g10_ = P[(A1)*6+1] + P[(A0)*6+2]; \
  const float e0_ = P[(M0)*6+3], e1_ = P[(M1)*6+3], e2_ = P[(M2)*6+3]; \
  const float h12_ = P[(M1)*6+4] + P[(M2)*6+5]; \
  const float h21_ = P[(M2)*6+4] + P[(M1)*6+5]; \
  const float h02_ = P[(M0)*6+4] + P[(M2)*6+5]; \
  const float h20_ = P[(M2)*6+4] + P[(M0)*6+5]; \
  const float h01_ = P[(M0)*6+4] + P[(M1)*6+5]; \
  const float h10_ = P[(M1)*6+4] + P[(M0)*6+5]; \
  const float T0_ = e0_+h12_, T1_ = e0_+h21_, T2_ = e1_+h02_; \
  const float T3_ = e1_+h20_, T4_ = e2_+h01_, T5_ = e2_+h10_; \
  PK3(k0,k1,k2,   f0_+g12_)  PK3(k3,k4,k5,   f0_+g21_) \
  PK3(k6,k7,k8,   f1_+g02_)  PK3(k9,k10,k11, f1_+g20_) \
  PK3(k12,k13,k14,f2_+g01_)  PK3(k15,k16,k17,f2_+g10_) }

// 16 slot-writes via 8 shared bases (swz class j) -> LLVM fuses (j, j+8) into
// ds_write2st64_b32. Layout idx = r2*64 + (lane^((r2&7)<<3)) — R11-verified.
#define WRT16(BB) { \
  bp0[(BB+0)*64]=k0;  bp0[(BB+8)*64]=k8;  \
  bp1[(BB+1)*64]=k1;  bp1[(BB+9)*64]=k9;  \
  bp2[(BB+2)*64]=k2;  bp2[(BB+10)*64]=k10; \
  bp3[(BB+3)*64]=k3;  bp3[(BB+11)*64]=k11; \
  bp4[(BB+4)*64]=k4;  bp4[(BB+12)*64]=k12; \
  bp5[(BB+5)*64]=k5;  bp5[(BB+13)*64]=k13; \
  bp6[(BB+6)*64]=k6;  bp6[(BB+14)*64]=k14; \
  bp7[(BB+7)*64]=k7;  bp7[(BB+15)*64]=k15; }

#define WOV(RA, RB) { \
  wb[(RA)*64 + (lane ^ ((((RA)) & 7) << 3))] = k16; \
  wb[(RB)*64 + (lane ^ ((((RB)) & 7) << 3))] = k17; }

// hi-only layer-2 tile: 4 MFMA + relu-accumulate (R9/R11-verified).
#define MFMA4T(A0_, A1_) do { \
  f32x4 c0_ = {b2v0,b2v0,b2v0,b2v0}; \
  f32x4 c1_ = {b2v1,b2v1,b2v1,b2v1}; \
  c0_ = __builtin_amdgcn_mfma_f32_16x16x32_bf16(A0_, bh00, c0_, 0,0,0); \
  c0_ = __builtin_amdgcn_mfma_f32_16x16x32_bf16(A1_, bh10, c0_, 0,0,0); \
  c1_ = __builtin_amdgcn_mfma_f32_16x16x32_bf16(A0_, bh01, c1_, 0,0,0); \
  c1_ = __builtin_amdgcn_mfma_f32_16x16x32_bf16(A1_, bh11, c1_, 0,0,0); \
  acc0[0]+=fmaxf(c0_[0],0.f); acc0[1]+=fmaxf(c0_[1],0.f); \
  acc0[2]+=fmaxf(c0_[2],0.f); acc0[3]+=fmaxf(c0_[3],0.f); \
  acc1[0]+=fmaxf(c1_[0],0.f); acc1[1]+=fmaxf(c1_[1],0.f); \
  acc1[2]+=fmaxf(c1_[2],0.f); acc1[3]+=fmaxf(c1_[3],0.f); \
} while(0)

// Queue 12 b128 reads for 3 tiles starting at u32 base B (R11-verified pattern).
#define RQ(B) { \
  q0  = *(const u32x4*)&wb[(B)+e0b];       q1  = *(const u32x4*)&wb[(B)+e0b+4]; \
  q2  = *(const u32x4*)&wb[(B)+e1b];       q3  = *(const u32x4*)&wb[(B)+e1b+4]; \
  q4  = *(const u32x4*)&wb[(B)+512+e0b];   q5  = *(const u32x4*)&wb[(B)+512+e0b+4]; \
  q6  = *(const u32x4*)&wb[(B)+512+e1b];   q7  = *(const u32x4*)&wb[(B)+512+e1b+4]; \
  q8  = *(const u32x4*)&wb[(B)+1024+e0b];  q9  = *(const u32x4*)&wb[(B)+1024+e0b+4]; \
  q10 = *(const u32x4*)&wb[(B)+1024+e1b];  q11 = *(const u32x4*)&wb[(B)+1024+e1b+4]; }

#define FRAG(dst, qa_, qb_) { \
  u32x4 t_; \
  t_[0] = __builtin_amdgcn_perm(qa_[1], qa_[0], sel); \
  t_[1] = __builtin_amdgcn_perm(qa_[3], qa_[2], sel); \
  t_[2] = __builtin_amdgcn_perm(qb_[1], qb_[0], sel); \
  t_[3] = __builtin_amdgcn_perm(qb_[3], qb_[2], sel); \
  dst = __builtin_bit_cast(short8, t_); }

#define M3 { \
  short8 A0f_, A1f_; \
  FRAG(A0f_, q0, q1);   FRAG(A1f_, q2, q3);   MFMA4T(A0f_, A1f_); \
  FRAG(A0f_, q4, q5);   FRAG(A1f_, q6, q7);   MFMA4T(A0f_, A1f_); \
  FRAG(A0f_, q8, q9);   FRAG(A1f_, q10, q11); MFMA4T(A0f_, A1f_); }

// Zero pad blocks r2=18..23 for chunkB (after chunkA's reads, DS in-order).
#define ZPAD6 { \
  wb[18*64+(lane^16)]=0u; wb[19*64+(lane^24)]=0u; wb[20*64+(lane^32)]=0u; \
  wb[21*64+(lane^40)]=0u; wb[22*64+(lane^48)]=0u; wb[23*64+(lane^56)]=0u; }

#define MKB(dst_h, KH, NIDX) do { \
  _Pragma("unroll") \
  for (int e_ = 0; e_ < 8; ++e_) { \
    float f_ = W2[((KH)*32 + kg*8 + e_)*32 + 16*(NIDX) + colb]; \
    __hip_bfloat16 hi_ = __float2bfloat16(f_); \
    dst_h[e_] = *(short*)&hi_; \
  } \
} while(0)

// (256,2): VGPR cap 256 (~180 needed). (256,4) forced 64 VGPR -> spills (R5);
// (256,3)'s 170 cap regressed (R14). 2 blocks/CU.
__global__ __launch_bounds__(256, 2) void symm_mlp_kernel(
    const float* __restrict__ x,
    const float* __restrict__ W1, const float* __restrict__ b1,
    const float* __restrict__ W2, const float* __restrict__ b2,
    const float* __restrict__ W3, const float* __restrict__ b3,
    const int* __restrict__ idx,
    float* __restrict__ out)
{
    __shared__ u32 h1s[4][72 * 64];   // per-wave 144-row pair-packed buffer (18 KB)
    __shared__ float redbuf[4][32];

    const int tid   = threadIdx.x;
    const int lane  = tid & 63;
    const int wv    = tid >> 6;
    const int batch = blockIdx.x;

    // ---- issue long-latency loads early ----
    int pidx[6];
    #pragma unroll
    for (int k = 0; k < 6; ++k) pidx[k] = idx[batch * 6 + k];

    float px[6][3];
    #pragma unroll
    for (int k = 0; k < 6; ++k)
        #pragma unroll
        for (int d = 0; d < 3; ++d) px[k][d] = x[(batch * NN + pidx[k]) * 3 + d];

    float w1c[18];
    #pragma unroll
    for (int r = 0; r < 18; ++r) w1c[r] = W1[r * 64 + lane];

    const float b1v = b1[lane];
    const int colb = lane & 15, kg = lane >> 4;
    const float b2v0 = b2[colb];
    const float b2v1 = b2[16 + colb];

    // ---- W2 hi-bf16 B-fragments (R9-verified accuracy) ----
    short8 bh00, bh10, bh01, bh11;
    MKB(bh00, 0, 0);
    MKB(bh10, 1, 0);
    MKB(bh01, 0, 1);
    MKB(bh11, 1, 1);

    // ---- P[k*6+j] = pts[k] . W1[3j:3j+3, h=lane] (registers, R11-verified) ----
    float P[36];
    #pragma unroll
    for (int k = 0; k < 6; ++k)
    #pragma unroll
    for (int j = 0; j < 6; ++j)
        P[k*6+j] = fmaf(px[k][2], w1c[3*j+2], fmaf(px[k][1], w1c[3*j+1], px[k][0] * w1c[3*j+0]));

    // LDS bases: per-swizzle-class write pointers + read offsets (R11-verified).
    u32* wb  = &h1s[wv][0];
    u32* bp0 = wb + (lane ^ 0);
    u32* bp1 = wb + (lane ^ 8);
    u32* bp2 = wb + (lane ^ 16);
    u32* bp3 = wb + (lane ^ 24);
    u32* bp4 = wb + (lane ^ 32);
    u32* bp5 = wb + (lane ^ 40);
    u32* bp6 = wb + (lane ^ 48);
    u32* bp7 = wb + (lane ^ 56);

    const int r2l = (lane & 15) >> 1;
    const int sm  = r2l << 3;
    const int e0b = r2l * 64 + ((kg * 8) ^ sm);
    const int e1b = r2l * 64 + ((32 + kg * 8) ^ sm);
    const u32 sel = (lane & 1) ? 0x07060302u : 0x05040100u;

    f32x4 acc0 = {0.f,0.f,0.f,0.f}, acc1 = {0.f,0.f,0.f,0.f};
    u32x4 q0,q1,q2,q3,q4,q5,q6,q7,q8,q9,q10,q11;
    u32 k0,k1,k2,k3,k4,k5,k6,k7,k8,k9,k10,k11,k12,k13,k14,k15,k16,k17;

    // ---- chunkA: 4 supergroups -> 144 rows = 9 full tiles (no pad) ----
    // SG i slots: r2 = 16i+j (j=0..15, write2st64 pairs) + overflow 64+2i, 65+2i.
    if (wv == 0) {
        SGCOMP(0,1,2, 3,4,5); WRT16(0);  WOV(64,65);
        SGCOMP(0,1,3, 2,4,5); WRT16(16); WOV(66,67);
        SGCOMP(0,1,4, 2,3,5); WRT16(32); WOV(68,69);
        SGCOMP(0,1,5, 2,3,4); WRT16(48); WOV(70,71);
    } else if (wv == 1) {
        SGCOMP(0,2,4, 1,3,5); WRT16(0);  WOV(64,65);
        SGCOMP(0,2,5, 1,3,4); WRT16(16); WOV(66,67);
        SGCOMP(0,3,4, 1,2,5); WRT16(32); WOV(68,69);
        SGCOMP(0,3,5, 1,2,4); WRT16(48); WOV(70,71);
    } else if (wv == 2) {
        SGCOMP(1,2,3, 0,4,5); WRT16(0);  WOV(64,65);
        SGCOMP(1,2,4, 0,3,5); WRT16(16); WOV(66,67);
        SGCOMP(1,2,5, 0,3,4); WRT16(32); WOV(68,69);
        SGCOMP(1,3,4, 0,2,5); WRT16(48); WOV(70,71);
    } else {
        SGCOMP(1,4,5, 0,2,3); WRT16(0);  WOV(64,65);
        SGCOMP(2,3,4, 0,1,5); WRT16(16); WOV(66,67);
        SGCOMP(2,3,5, 0,1,4); WRT16(32); WOV(68,69);
        SGCOMP(2,4,5, 0,1,3); WRT16(48); WOV(70,71);
    }
    SFENCE;            // pin: all chunkA writes issue before chunkA reads
    RQ(0);    M3;      // compiler inserts counted lgkmcnt before MFMA operands
    RQ(1536); M3;
    RQ(3072); M3;
    SFENCE;            // pin: chunkA reads issue before chunkB writes (WAR)

    // ---- chunkB: 5th supergroup (36 rows + 12 pad) ----
    ZPAD6;
    if (wv == 0)      { SGCOMP(0,2,3, 1,4,5); }
    else if (wv == 1) { SGCOMP(0,4,5, 1,2,3); }
    else if (wv == 2) { SGCOMP(1,3,5, 0,2,4); }
    else              { SGCOMP(3,4,5, 0,1,2); }
    WRT16(0); WOV(16,17);
    SFENCE;            // pin: chunkB writes before chunkB reads
    RQ(0); M3;

    // ---- wave-level reduce (180 real + 12 zero-pad rows each) ----
    float s0 = acc0[0] + acc0[1] + acc0[2] + acc0[3];
    float s1 = acc1[0] + acc1[1] + acc1[2] + acc1[3];
    s0 += __shfl_xor(s0, 16, 64);  s0 += __shfl_xor(s0, 32, 64);
    s1 += __shfl_xor(s1, 16, 64);  s1 += __shfl_xor(s1, 32, 64);
    // pad rows contributed relu(b2[col]) each: 12 pad rows (chunkB tiles)
    s0 -= 12.0f * fmaxf(b2v0, 0.0f);
    s1 -= 12.0f * fmaxf(b2v1, 0.0f);

    if (lane < 16)       redbuf[wv][lane] = s0;
    else if (lane < 32)  redbuf[wv][lane] = s1;
    __syncthreads();

    // ---- combine waves + layer 3, once per batch ----
    if (tid < 40) {
        float m[32];
        #pragma unroll
        for (int c = 0; c < 32; ++c)
            m[c] = (redbuf[0][c] + redbuf[1][c] + redbuf[2][c] + redbuf[3][c]) * (1.0f / 720.0f);
        float y = b3[tid];
        #pragma unroll
        for (int c = 0; c < 32; ++c) y = fmaf(m[c], W3[c * 40 + tid], y);
        out[batch * 40 + tid] = y;
    }
}

extern "C" void kernel_launch(void* const* d_in, const int* in_sizes, int n_in,
                              void* d_out, int out_size, void* d_ws, size_t ws_size,
                              hipStream_t stream) {
    const float* x  = (const float*)d_in[0];
    const float* W1 = (const float*)d_in[1];
    const float* b1 = (const float*)d_in[2];
    const float* W2 = (const float*)d_in[3];
    const float* b2 = (const float*)d_in[4];
    const float* W3 = (const float*)d_in[5];
    const float* b3 = (const float*)d_in[6];
    const int* idx   = (const int*)d_in[7];
    // d_in[8] (perms) is a compile-time constant (all perms of 0..5); the mean
    // over permutations is order-invariant, so enumeration is hard-coded.
    float* out = (float*)d_out;

    symm_mlp_kernel<<<1024, 256, 0, stream>>>(x, W1, b1, W2, b2, W3, b3, idx, out);
}